// Round 1
// baseline (5001.677 us; speedup 1.0000x reference)
//
#include <hip/hip_runtime.h>
#include <cstddef>
#include <cstdint>

#define BN_EPS 1e-5f

constexpr int TM = 64, TN = 64, TK = 16;

// Implicit-GEMM conv1d + folded BN + ReLU.
// out[b][co][t] = relu( BN( sum_{ci,kw} w[co][ci][kw] * in[b][ci][t*S + kw - P] ) )
template<int KW, int STRIDE, int PAD>
__global__ __launch_bounds__(256)
void conv_bn_relu_gemm(const float* __restrict__ in, const float* __restrict__ w,
                       const float* __restrict__ gamma, const float* __restrict__ beta,
                       const float* __restrict__ mean, const float* __restrict__ var,
                       float* __restrict__ out,
                       int Cin, int Tin, int Cout, int Tout)
{
    const int b   = blockIdx.z;
    const int co0 = blockIdx.x * TM;
    const int t0  = blockIdx.y * TN;
    const int Kg  = Cin * KW;
    const int tid = threadIdx.x;

    __shared__ float As[TK][TM + 4];   // As[kk][m] = w[co0+m][kc+kk]
    __shared__ float Bs[TK][TN + 4];   // Bs[kk][n] = im2col

    float acc[4][4] = {};

    const int m0 = (tid & 15) * 4;
    const int n0 = (tid >> 4) * 4;

    const float* __restrict__ inb = in + (size_t)b * Cin * Tin;

    const int a_m = tid >> 4;   // + 16*i
    const int a_k = tid & 15;
    const int b_k = tid >> 6;   // + 4*i
    const int b_n = tid & 63;

    for (int kc = 0; kc < Kg; kc += TK) {
        __syncthreads();
#pragma unroll
        for (int i = 0; i < 4; ++i) {
            int m = a_m + 16 * i;
            As[a_k][m] = w[(size_t)(co0 + m) * Kg + kc + a_k];
        }
#pragma unroll
        for (int i = 0; i < 4; ++i) {
            int kk  = b_k + 4 * i;
            int cik = kc + kk;
            int ci  = cik / KW;
            int kw  = cik - ci * KW;
            int tin = (t0 + b_n) * STRIDE + kw - PAD;
            float v = 0.0f;
            if (tin >= 0 && tin < Tin) v = inb[(size_t)ci * Tin + tin];
            Bs[kk][b_n] = v;
        }
        __syncthreads();
#pragma unroll
        for (int kk = 0; kk < TK; ++kk) {
            float4 av = *reinterpret_cast<const float4*>(&As[kk][m0]);
            float4 bv = *reinterpret_cast<const float4*>(&Bs[kk][n0]);
            float am[4] = {av.x, av.y, av.z, av.w};
            float bn[4] = {bv.x, bv.y, bv.z, bv.w};
#pragma unroll
            for (int mi = 0; mi < 4; ++mi)
#pragma unroll
                for (int nj = 0; nj < 4; ++nj)
                    acc[mi][nj] = fmaf(am[mi], bn[nj], acc[mi][nj]);
        }
    }

#pragma unroll
    for (int mi = 0; mi < 4; ++mi) {
        int co = co0 + m0 + mi;
        float g  = gamma[co], be = beta[co], mu = mean[co], va = var[co];
        float inv = g / sqrtf(va + BN_EPS);
        float sh  = be - mu * inv;
        float* op = out + ((size_t)b * Cout + co) * Tout;
#pragma unroll
        for (int nj = 0; nj < 4; ++nj) {
            int t = t0 + n0 + nj;
            if (t < Tout) {
                float v = acc[mi][nj] * inv + sh;
                op[t] = v > 0.0f ? v : 0.0f;
            }
        }
    }
}

// 1x1 conv (C=768 -> D=64) + bias, output transposed to z[b][t][d]
__global__ __launch_bounds__(256)
void conv1x1_bias_T(const float* __restrict__ in, const float* __restrict__ w,
                    const float* __restrict__ bias, float* __restrict__ z,
                    int Cin, int T)
{
    const int b   = blockIdx.z;
    const int t0  = blockIdx.y * TN;
    const int tid = threadIdx.x;

    __shared__ float As[TK][TM + 4];
    __shared__ float Bs[TK][TN + 4];

    float acc[4][4] = {};

    const int m0 = (tid & 15) * 4;
    const int n0 = (tid >> 4) * 4;

    const float* __restrict__ inb = in + (size_t)b * Cin * T;

    const int a_m = tid >> 4;
    const int a_k = tid & 15;
    const int b_k = tid >> 6;
    const int b_n = tid & 63;

    for (int kc = 0; kc < Cin; kc += TK) {
        __syncthreads();
#pragma unroll
        for (int i = 0; i < 4; ++i) {
            int m = a_m + 16 * i;
            As[a_k][m] = w[(size_t)m * Cin + kc + a_k];
        }
#pragma unroll
        for (int i = 0; i < 4; ++i) {
            int kk = b_k + 4 * i;
            int ci = kc + kk;
            int t  = t0 + b_n;
            Bs[kk][b_n] = (t < T) ? inb[(size_t)ci * T + t] : 0.0f;
        }
        __syncthreads();
#pragma unroll
        for (int kk = 0; kk < TK; ++kk) {
            float4 av = *reinterpret_cast<const float4*>(&As[kk][m0]);
            float4 bv = *reinterpret_cast<const float4*>(&Bs[kk][n0]);
            float am[4] = {av.x, av.y, av.z, av.w};
            float bn[4] = {bv.x, bv.y, bv.z, bv.w};
#pragma unroll
            for (int mi = 0; mi < 4; ++mi)
#pragma unroll
                for (int nj = 0; nj < 4; ++nj)
                    acc[mi][nj] = fmaf(am[mi], bn[nj], acc[mi][nj]);
        }
    }

    float4 bb = *reinterpret_cast<const float4*>(&bias[m0]);
    float bs[4] = {bb.x, bb.y, bb.z, bb.w};
#pragma unroll
    for (int nj = 0; nj < 4; ++nj) {
        int t = t0 + n0 + nj;
        if (t < T) {
            float4 v;
            v.x = acc[0][nj] + bs[0];
            v.y = acc[1][nj] + bs[1];
            v.z = acc[2][nj] + bs[2];
            v.w = acc[3][nj] + bs[3];
            *reinterpret_cast<float4*>(&z[((size_t)b * T + t) * 64 + m0]) = v;
        }
    }
}

__global__ __launch_bounds__(256)
void vq_e2(const float* __restrict__ emb, float* __restrict__ e2)
{
    int m = blockIdx.x * 256 + threadIdx.x;
    if (m < 512) {
        float s = 0.0f;
#pragma unroll
        for (int d = 0; d < 64; ++d) {
            float v = emb[(size_t)m * 64 + d];
            s = fmaf(v, v, s);
        }
        e2[m] = s;
    }
}

// one wave per block; each thread owns one point (D=64 in registers)
__global__ __launch_bounds__(64)
void vq_argmin(const float* __restrict__ z, const float* __restrict__ emb,
               const float* __restrict__ e2, int* __restrict__ idx,
               float* __restrict__ counts, int N)
{
    __shared__ float Es[64 * 64];
    const int tid = threadIdx.x;
    const int n   = blockIdx.x * 64 + tid;
    const bool act = n < N;

    float x[64];
    float x2 = 0.0f;
    if (act) {
        const float4* zp = reinterpret_cast<const float4*>(z + (size_t)n * 64);
#pragma unroll
        for (int i = 0; i < 16; ++i) {
            float4 v = zp[i];
            x[4 * i + 0] = v.x; x[4 * i + 1] = v.y;
            x[4 * i + 2] = v.z; x[4 * i + 3] = v.w;
        }
#pragma unroll
        for (int d = 0; d < 64; ++d) x2 = fmaf(x[d], x[d], x2);
    }

    float best = 3.4e38f;
    int   bi   = 0;
    for (int c = 0; c < 8; ++c) {
        __syncthreads();
        const float4* ep  = reinterpret_cast<const float4*>(emb + (size_t)c * 4096);
        float4*       esp = reinterpret_cast<float4*>(Es);
#pragma unroll
        for (int i = 0; i < 16; ++i) esp[tid + 64 * i] = ep[tid + 64 * i];
        __syncthreads();
        for (int r = 0; r < 64; ++r) {
            const float4* er = reinterpret_cast<const float4*>(&Es[r * 64]);
            float dot = 0.0f;
#pragma unroll
            for (int i = 0; i < 16; ++i) {
                float4 e4 = er[i];
                dot = fmaf(x[4 * i + 0], e4.x, dot);
                dot = fmaf(x[4 * i + 1], e4.y, dot);
                dot = fmaf(x[4 * i + 2], e4.z, dot);
                dot = fmaf(x[4 * i + 3], e4.w, dot);
            }
            // replicate reference rounding: (||e||^2 + ||x||^2) - 2*x.e
            float dist = (e2[c * 64 + r] + x2) - 2.0f * dot;
            if (dist < best) { best = dist; bi = c * 64 + r; }  // first-min
        }
    }
    if (act) {
        idx[n] = bi;
        atomicAdd(&counts[bi], 1.0f);   // exact small integers in fp32
    }
}

__global__ __launch_bounds__(256)
void vq_quant_loss(const float* __restrict__ z, const float* __restrict__ emb,
                   const int* __restrict__ idx, float* __restrict__ qout,
                   double* __restrict__ loss_sum, int Ntot)
{
    int g = blockIdx.x * 256 + threadIdx.x;
    float d2 = 0.0f;
    if (g < Ntot) {
        int n = g >> 6;
        int d = g & 63;
        float q  = emb[(size_t)idx[n] * 64 + d];
        float zv = z[g];
        qout[g] = zv + (q - zv);        // straight-through, matches reference op order
        float diff = zv - q;
        d2 = diff * diff;
    }
#pragma unroll
    for (int o = 32; o > 0; o >>= 1) d2 += __shfl_down(d2, o);
    __shared__ float wsum[4];
    if ((threadIdx.x & 63) == 0) wsum[threadIdx.x >> 6] = d2;
    __syncthreads();
    if (threadIdx.x == 0)
        atomicAdd(loss_sum, (double)(wsum[0] + wsum[1] + wsum[2] + wsum[3]));
}

__global__ __launch_bounds__(512)
void vq_finalize(const float* __restrict__ counts, const double* __restrict__ loss_sum,
                 float* __restrict__ out, int Ntot, int Npts)
{
    int t = threadIdx.x;
    float c   = counts[t];
    float avg = c / (float)Npts;
    float term = avg * logf(avg + 1e-10f);
#pragma unroll
    for (int o = 32; o > 0; o >>= 1) term += __shfl_down(term, o);
    __shared__ float wsum[8];
    if ((t & 63) == 0) wsum[t >> 6] = term;
    __syncthreads();
    if (t == 0) {
        float s = 0.0f;
        for (int i = 0; i < 8; ++i) s += wsum[i];
        out[Ntot]     = 0.25f * (float)(loss_sum[0] / (double)Ntot);
        out[Ntot + 1] = expf(-s);
    }
}

extern "C" void kernel_launch(void* const* d_in, const int* in_sizes, int n_in,
                              void* d_out, int out_size, void* d_ws, size_t ws_size,
                              hipStream_t stream)
{
    const float* mels     = (const float*)d_in[0];
    const float* w1       = (const float*)d_in[1];
    const float* w2       = (const float*)d_in[2];
    const float* w3       = (const float*)d_in[3];
    const float* w4       = (const float*)d_in[4];
    const float* w5       = (const float*)d_in[5];
    const float* w6       = (const float*)d_in[6];
    const float* b6       = (const float*)d_in[7];
    const float* bn_gamma = (const float*)d_in[8];
    const float* bn_beta  = (const float*)d_in[9];
    const float* bn_mean  = (const float*)d_in[10];
    const float* bn_var   = (const float*)d_in[11];
    const float* emb      = (const float*)d_in[12];

    constexpr int B = 32, C = 768, D = 64;
    constexpr int T1 = 1022, T2 = 511;
    constexpr size_t ACT = (size_t)B * C * T1;          // 25,116,672 floats

    char* ws = (char*)d_ws;
    float*  bufA   = (float*)ws;
    float*  bufB   = (float*)(ws + ACT * 4);
    size_t  zoff   = 2 * ACT * 4;
    float*  z      = (float*)(ws + zoff);
    size_t  idxoff = zoff + (size_t)B * T2 * D * 4;
    int*    idx    = (int*)(ws + idxoff);
    size_t  e2off  = idxoff + (size_t)B * T2 * 4;
    float*  e2p    = (float*)(ws + e2off);
    size_t  cntoff = e2off + 512 * 4;
    float*  counts = (float*)(ws + cntoff);
    double* lossp  = (double*)(ws + cntoff + 512 * 4);

    // zero counts (512 f) + loss accumulator (1 double)
    hipMemsetAsync(ws + cntoff, 0, 512 * 4 + 8, stream);

    vq_e2<<<dim3(2), 256, 0, stream>>>(emb, e2p);

    conv_bn_relu_gemm<3, 1, 0><<<dim3(12, 16, B), 256, 0, stream>>>(
        mels, w1, bn_gamma + 0 * C, bn_beta + 0 * C, bn_mean + 0 * C, bn_var + 0 * C,
        bufA, 80, 1024, C, T1);
    conv_bn_relu_gemm<3, 1, 1><<<dim3(12, 16, B), 256, 0, stream>>>(
        bufA, w2, bn_gamma + 1 * C, bn_beta + 1 * C, bn_mean + 1 * C, bn_var + 1 * C,
        bufB, C, T1, C, T1);
    conv_bn_relu_gemm<4, 2, 1><<<dim3(12, 8, B), 256, 0, stream>>>(
        bufB, w3, bn_gamma + 2 * C, bn_beta + 2 * C, bn_mean + 2 * C, bn_var + 2 * C,
        bufA, C, T1, C, T2);
    conv_bn_relu_gemm<3, 1, 1><<<dim3(12, 8, B), 256, 0, stream>>>(
        bufA, w4, bn_gamma + 3 * C, bn_beta + 3 * C, bn_mean + 3 * C, bn_var + 3 * C,
        bufB, C, T2, C, T2);
    conv_bn_relu_gemm<3, 1, 1><<<dim3(12, 8, B), 256, 0, stream>>>(
        bufB, w5, bn_gamma + 4 * C, bn_beta + 4 * C, bn_mean + 4 * C, bn_var + 4 * C,
        bufA, C, T2, C, T2);

    conv1x1_bias_T<<<dim3(1, 8, B), 256, 0, stream>>>(bufA, w6, b6, z, C, T2);

    const int Npts = B * T2;              // 16352
    const int Ntot = Npts * D;            // 1,046,528
    vq_argmin<<<dim3((Npts + 63) / 64), 64, 0, stream>>>(z, emb, e2p, idx, counts, Npts);
    vq_quant_loss<<<dim3(Ntot / 256), 256, 0, stream>>>(z, emb, idx, (float*)d_out, lossp, Ntot);
    vq_finalize<<<dim3(1), 512, 0, stream>>>(counts, lossp, (float*)d_out, Ntot, Npts);
}

// Round 2
// 4404.802 us; speedup vs baseline: 1.1355x; 1.1355x over previous
//
#include <hip/hip_runtime.h>
#include <cstddef>
#include <cstdint>

#define BN_EPS 1e-5f

// ============ 128x128 block tile, 8x8 per thread, fp32 implicit-GEMM conv ===
// out[b][co][t] = relu( BN( sum_{ci,kw} w[co][ci][kw] * in[b][ci][t*S+kw-P] ) )
template<int KW, int STRIDE, int PAD>
__global__ __launch_bounds__(256)
void conv_bn_relu_gemm128(const float* __restrict__ in, const float* __restrict__ w,
                          const float* __restrict__ gamma, const float* __restrict__ beta,
                          const float* __restrict__ mean, const float* __restrict__ var,
                          float* __restrict__ out,
                          int Cin, int Tin, int Cout, int Tout)
{
    constexpr int BK = 16;
    const int b   = blockIdx.z;
    const int co0 = blockIdx.x * 128;
    const int t0  = blockIdx.y * 128;
    const int Kg  = Cin * KW;
    const int tid = threadIdx.x;

    __shared__ float As[BK][132];   // As[kk][m] = w[co0+m][kc+kk]
    __shared__ float Bs[BK][132];   // Bs[kk][n] = im2col input

    float acc[8][8] = {};

    const int tx = tid & 15;        // n-group: cols tx*4..+3 and +64
    const int ty = tid >> 4;        // m-group: rows ty*4..+3 and +64

    const float* __restrict__ inb = in + (size_t)b * Cin * Tin;

    // A staging: each thread loads 8 contiguous K-floats of one weight row
    const int a_row  = tid >> 1;          // 0..127
    const int a_col0 = (tid & 1) * 8;     // 0 or 8
    const float* __restrict__ wrow = w + (size_t)(co0 + a_row) * Kg + a_col0;

    // B staging: each thread loads 8 consecutive-n values for one kk
    const int b_kk = tid >> 4;            // 0..15
    const int b_nb = (tid & 15) * 8;      // 0..120

    float4 rA0, rA1;
    float  rB[8];

    auto loadA = [&](int kc) {
        const float* p = wrow + kc;       // 16B-aligned: Kg%16==0, col0%4==0
        rA0 = *reinterpret_cast<const float4*>(p);
        rA1 = *reinterpret_cast<const float4*>(p + 4);
    };
    auto loadB = [&](int kc) {
        int cik = kc + b_kk;
        int ci  = cik / KW;               // KW is a compile-time constant
        int kw  = cik - ci * KW;
        const float* __restrict__ pc = inb + (size_t)ci * Tin;
        int tin0 = (t0 + b_nb) * STRIDE + kw - PAD;
#pragma unroll
        for (int j = 0; j < 8; ++j) {
            int tin = tin0 + j * STRIDE;
            rB[j] = (tin >= 0 && tin < Tin) ? pc[tin] : 0.0f;
        }
    };

    loadA(0);
    loadB(0);

    for (int kc = 0; kc < Kg; kc += BK) {
        __syncthreads();                  // previous compute done
        {
            float av[8] = {rA0.x, rA0.y, rA0.z, rA0.w, rA1.x, rA1.y, rA1.z, rA1.w};
#pragma unroll
            for (int j = 0; j < 8; ++j) As[a_col0 + j][a_row] = av[j];
            *reinterpret_cast<float4*>(&Bs[b_kk][b_nb])     = make_float4(rB[0], rB[1], rB[2], rB[3]);
            *reinterpret_cast<float4*>(&Bs[b_kk][b_nb + 4]) = make_float4(rB[4], rB[5], rB[6], rB[7]);
        }
        __syncthreads();
        if (kc + BK < Kg) { loadA(kc + BK); loadB(kc + BK); }  // reg prefetch

#pragma unroll
        for (int kk = 0; kk < BK; ++kk) {
            float4 a0 = *reinterpret_cast<const float4*>(&As[kk][ty * 4]);
            float4 a1 = *reinterpret_cast<const float4*>(&As[kk][ty * 4 + 64]);
            float4 b0 = *reinterpret_cast<const float4*>(&Bs[kk][tx * 4]);
            float4 b1 = *reinterpret_cast<const float4*>(&Bs[kk][tx * 4 + 64]);
            float a[8]  = {a0.x, a0.y, a0.z, a0.w, a1.x, a1.y, a1.z, a1.w};
            float bb[8] = {b0.x, b0.y, b0.z, b0.w, b1.x, b1.y, b1.z, b1.w};
#pragma unroll
            for (int mi = 0; mi < 8; ++mi)
#pragma unroll
                for (int nj = 0; nj < 8; ++nj)
                    acc[mi][nj] = fmaf(a[mi], bb[nj], acc[mi][nj]);
        }
    }

#pragma unroll
    for (int mi = 0; mi < 8; ++mi) {
        int co = co0 + ty * 4 + (mi & 3) + (mi >> 2) * 64;
        float g  = gamma[co], be = beta[co], mu = mean[co], va = var[co];
        float inv = g / sqrtf(va + BN_EPS);
        float sh  = be - mu * inv;
        float* op = out + ((size_t)b * Cout + co) * Tout;
#pragma unroll
        for (int nj = 0; nj < 8; ++nj) {
            int t = t0 + tx * 4 + (nj & 3) + (nj >> 2) * 64;
            if (t < Tout) {
                float v = acc[mi][nj] * inv + sh;
                op[t] = v > 0.0f ? v : 0.0f;
            }
        }
    }
}

// ================= 1x1 conv (C=768 -> D=64) + bias, output z[b][t][d] =======
constexpr int TM = 64, TN = 64, TK = 16;

__global__ __launch_bounds__(256)
void conv1x1_bias_T(const float* __restrict__ in, const float* __restrict__ w,
                    const float* __restrict__ bias, float* __restrict__ z,
                    int Cin, int T)
{
    const int b   = blockIdx.z;
    const int t0  = blockIdx.y * TN;
    const int tid = threadIdx.x;

    __shared__ float As[TK][TM + 4];
    __shared__ float Bs[TK][TN + 4];

    float acc[4][4] = {};

    const int m0 = (tid & 15) * 4;
    const int n0 = (tid >> 4) * 4;

    const float* __restrict__ inb = in + (size_t)b * Cin * T;

    const int a_m = tid >> 4;
    const int a_k = tid & 15;
    const int b_k = tid >> 6;
    const int b_n = tid & 63;

    for (int kc = 0; kc < Cin; kc += TK) {
        __syncthreads();
#pragma unroll
        for (int i = 0; i < 4; ++i) {
            int m = a_m + 16 * i;
            As[a_k][m] = w[(size_t)m * Cin + kc + a_k];
        }
#pragma unroll
        for (int i = 0; i < 4; ++i) {
            int kk = b_k + 4 * i;
            int ci = kc + kk;
            int t  = t0 + b_n;
            Bs[kk][b_n] = (t < T) ? inb[(size_t)ci * T + t] : 0.0f;
        }
        __syncthreads();
#pragma unroll
        for (int kk = 0; kk < TK; ++kk) {
            float4 av = *reinterpret_cast<const float4*>(&As[kk][m0]);
            float4 bv = *reinterpret_cast<const float4*>(&Bs[kk][n0]);
            float am[4] = {av.x, av.y, av.z, av.w};
            float bn[4] = {bv.x, bv.y, bv.z, bv.w};
#pragma unroll
            for (int mi = 0; mi < 4; ++mi)
#pragma unroll
                for (int nj = 0; nj < 4; ++nj)
                    acc[mi][nj] = fmaf(am[mi], bn[nj], acc[mi][nj]);
        }
    }

    float4 bb = *reinterpret_cast<const float4*>(&bias[m0]);
    float bs[4] = {bb.x, bb.y, bb.z, bb.w};
#pragma unroll
    for (int nj = 0; nj < 4; ++nj) {
        int t = t0 + n0 + nj;
        if (t < T) {
            float4 v;
            v.x = acc[0][nj] + bs[0];
            v.y = acc[1][nj] + bs[1];
            v.z = acc[2][nj] + bs[2];
            v.w = acc[3][nj] + bs[3];
            *reinterpret_cast<float4*>(&z[((size_t)b * T + t) * 64 + m0]) = v;
        }
    }
}

// ============================== VQ kernels ==================================
__global__ __launch_bounds__(256)
void vq_e2(const float* __restrict__ emb, float* __restrict__ e2)
{
    int m = blockIdx.x * 256 + threadIdx.x;
    if (m < 512) {
        float s = 0.0f;
#pragma unroll
        for (int d = 0; d < 64; ++d) {
            float v = emb[(size_t)m * 64 + d];
            s = fmaf(v, v, s);
        }
        e2[m] = s;
    }
}

__global__ __launch_bounds__(64)
void vq_argmin(const float* __restrict__ z, const float* __restrict__ emb,
               const float* __restrict__ e2, int* __restrict__ idx,
               float* __restrict__ counts, int N)
{
    __shared__ float Es[64 * 64];
    const int tid = threadIdx.x;
    const int n   = blockIdx.x * 64 + tid;
    const bool act = n < N;

    float x[64];
    float x2 = 0.0f;
    if (act) {
        const float4* zp = reinterpret_cast<const float4*>(z + (size_t)n * 64);
#pragma unroll
        for (int i = 0; i < 16; ++i) {
            float4 v = zp[i];
            x[4 * i + 0] = v.x; x[4 * i + 1] = v.y;
            x[4 * i + 2] = v.z; x[4 * i + 3] = v.w;
        }
#pragma unroll
        for (int d = 0; d < 64; ++d) x2 = fmaf(x[d], x[d], x2);
    }

    float best = 3.4e38f;
    int   bi   = 0;
    for (int c = 0; c < 8; ++c) {
        __syncthreads();
        const float4* ep  = reinterpret_cast<const float4*>(emb + (size_t)c * 4096);
        float4*       esp = reinterpret_cast<float4*>(Es);
#pragma unroll
        for (int i = 0; i < 16; ++i) esp[tid + 64 * i] = ep[tid + 64 * i];
        __syncthreads();
        for (int r = 0; r < 64; ++r) {
            const float4* er = reinterpret_cast<const float4*>(&Es[r * 64]);
            float dot = 0.0f;
#pragma unroll
            for (int i = 0; i < 16; ++i) {
                float4 e4 = er[i];
                dot = fmaf(x[4 * i + 0], e4.x, dot);
                dot = fmaf(x[4 * i + 1], e4.y, dot);
                dot = fmaf(x[4 * i + 2], e4.z, dot);
                dot = fmaf(x[4 * i + 3], e4.w, dot);
            }
            float dist = (e2[c * 64 + r] + x2) - 2.0f * dot;  // reference op order
            if (dist < best) { best = dist; bi = c * 64 + r; }
        }
    }
    if (act) {
        idx[n] = bi;
        atomicAdd(&counts[bi], 1.0f);
    }
}

__global__ __launch_bounds__(256)
void vq_quant_loss(const float* __restrict__ z, const float* __restrict__ emb,
                   const int* __restrict__ idx, float* __restrict__ qout,
                   double* __restrict__ loss_sum, int Ntot)
{
    int g = blockIdx.x * 256 + threadIdx.x;
    float d2 = 0.0f;
    if (g < Ntot) {
        int n = g >> 6;
        int d = g & 63;
        float q  = emb[(size_t)idx[n] * 64 + d];
        float zv = z[g];
        qout[g] = zv + (q - zv);
        float diff = zv - q;
        d2 = diff * diff;
    }
#pragma unroll
    for (int o = 32; o > 0; o >>= 1) d2 += __shfl_down(d2, o);
    __shared__ float wsum[4];
    if ((threadIdx.x & 63) == 0) wsum[threadIdx.x >> 6] = d2;
    __syncthreads();
    if (threadIdx.x == 0)
        atomicAdd(loss_sum, (double)(wsum[0] + wsum[1] + wsum[2] + wsum[3]));
}

__global__ __launch_bounds__(512)
void vq_finalize(const float* __restrict__ counts, const double* __restrict__ loss_sum,
                 float* __restrict__ out, int Ntot, int Npts)
{
    int t = threadIdx.x;
    float c   = counts[t];
    float avg = c / (float)Npts;
    float term = avg * logf(avg + 1e-10f);
#pragma unroll
    for (int o = 32; o > 0; o >>= 1) term += __shfl_down(term, o);
    __shared__ float wsum[8];
    if ((t & 63) == 0) wsum[t >> 6] = term;
    __syncthreads();
    if (t == 0) {
        float s = 0.0f;
        for (int i = 0; i < 8; ++i) s += wsum[i];
        out[Ntot]     = 0.25f * (float)(loss_sum[0] / (double)Ntot);
        out[Ntot + 1] = expf(-s);
    }
}

// ================================ launcher ==================================
extern "C" void kernel_launch(void* const* d_in, const int* in_sizes, int n_in,
                              void* d_out, int out_size, void* d_ws, size_t ws_size,
                              hipStream_t stream)
{
    const float* mels     = (const float*)d_in[0];
    const float* w1       = (const float*)d_in[1];
    const float* w2       = (const float*)d_in[2];
    const float* w3       = (const float*)d_in[3];
    const float* w4       = (const float*)d_in[4];
    const float* w5       = (const float*)d_in[5];
    const float* w6       = (const float*)d_in[6];
    const float* b6       = (const float*)d_in[7];
    const float* bn_gamma = (const float*)d_in[8];
    const float* bn_beta  = (const float*)d_in[9];
    const float* bn_mean  = (const float*)d_in[10];
    const float* bn_var   = (const float*)d_in[11];
    const float* emb      = (const float*)d_in[12];

    constexpr int B = 32, C = 768, D = 64;
    constexpr int T1 = 1022, T2 = 511;
    constexpr size_t ACT = (size_t)B * C * T1;

    char* ws = (char*)d_ws;
    float*  bufA   = (float*)ws;
    float*  bufB   = (float*)(ws + ACT * 4);
    size_t  zoff   = 2 * ACT * 4;
    float*  z      = (float*)(ws + zoff);
    size_t  idxoff = zoff + (size_t)B * T2 * D * 4;
    int*    idx    = (int*)(ws + idxoff);
    size_t  e2off  = idxoff + (size_t)B * T2 * 4;
    float*  e2p    = (float*)(ws + e2off);
    size_t  cntoff = e2off + 512 * 4;
    float*  counts = (float*)(ws + cntoff);
    double* lossp  = (double*)(ws + cntoff + 512 * 4);

    hipMemsetAsync(ws + cntoff, 0, 512 * 4 + 8, stream);

    vq_e2<<<dim3(2), 256, 0, stream>>>(emb, e2p);

    conv_bn_relu_gemm128<3, 1, 0><<<dim3(6, 8, B), 256, 0, stream>>>(
        mels, w1, bn_gamma + 0 * C, bn_beta + 0 * C, bn_mean + 0 * C, bn_var + 0 * C,
        bufA, 80, 1024, C, T1);
    conv_bn_relu_gemm128<3, 1, 1><<<dim3(6, 8, B), 256, 0, stream>>>(
        bufA, w2, bn_gamma + 1 * C, bn_beta + 1 * C, bn_mean + 1 * C, bn_var + 1 * C,
        bufB, C, T1, C, T1);
    conv_bn_relu_gemm128<4, 2, 1><<<dim3(6, 4, B), 256, 0, stream>>>(
        bufB, w3, bn_gamma + 2 * C, bn_beta + 2 * C, bn_mean + 2 * C, bn_var + 2 * C,
        bufA, C, T1, C, T2);
    conv_bn_relu_gemm128<3, 1, 1><<<dim3(6, 4, B), 256, 0, stream>>>(
        bufA, w4, bn_gamma + 3 * C, bn_beta + 3 * C, bn_mean + 3 * C, bn_var + 3 * C,
        bufB, C, T2, C, T2);
    conv_bn_relu_gemm128<3, 1, 1><<<dim3(6, 4, B), 256, 0, stream>>>(
        bufB, w5, bn_gamma + 4 * C, bn_beta + 4 * C, bn_mean + 4 * C, bn_var + 4 * C,
        bufA, C, T2, C, T2);

    conv1x1_bias_T<<<dim3(1, 8, B), 256, 0, stream>>>(bufA, w6, b6, z, C, T2);

    const int Npts = B * T2;
    const int Ntot = Npts * D;
    vq_argmin<<<dim3((Npts + 63) / 64), 64, 0, stream>>>(z, emb, e2p, idx, counts, Npts);
    vq_quant_loss<<<dim3(Ntot / 256), 256, 0, stream>>>(z, emb, idx, (float*)d_out, lossp, Ntot);
    vq_finalize<<<dim3(1), 512, 0, stream>>>(counts, lossp, (float*)d_out, Ntot, Npts);
}